// Round 1
// baseline (1214.856 us; speedup 1.0000x reference)
//
#include <hip/hip_runtime.h>
#include <math.h>

#define NB   16
#define HH   209
#define WW   133
#define CIN  64
#define COUT 128
#define OH   201
#define OW   129
#define NTAP 19
#define NW   (NTAP*CIN*COUT)

// hex taps for R=2 in the 9x5 kernel grid
__constant__ int c_dh[NTAP] = {4,3,5,6,5,3,2,1,2,4,6,7,8,7,6,4,2,1,0};
__constant__ int c_dw[NTAP] = {2,3,3,2,1,1,2,3,4,4,4,3,2,1,0,0,0,1,2};

// sparse_weights layout: [ci][co][k]  (idx = ci*2432 + co*19 + k)
// repack to wt[k][ci][co] for coalesced B-tile staging
__global__ __launch_bounds__(256) void repack_w(const float* __restrict__ w,
                                                float* __restrict__ wt) {
  int gid = blockIdx.x * 256 + threadIdx.x;
  if (gid >= NW) return;
  int ci  = gid / (COUT * NTAP);
  int rem = gid - ci * (COUT * NTAP);
  int co  = rem / NTAP;
  int k   = rem - co * NTAP;
  wt[(k * CIN + ci) * COUT + co] = w[gid];
}

// block: 256 threads -> tile of 32 active-parity columns x 128 co for one (b,oi) row.
// thread (tid): co_b=(tid&31)*4, p_b=(tid>>5)*4  -> 4x4 register tile.
template <bool PACKED>
__global__ __launch_bounds__(256) void conv_hex(const float* __restrict__ x,
                                                const float* __restrict__ w,
                                                const float* __restrict__ offs,
                                                float* __restrict__ out) {
  __shared__ float xs[32][CIN];     // 8 KB : 32 positions x 64 ci
  __shared__ float ws[CIN][COUT];   // 32 KB: 64 ci x 128 co (one tap)

  const int tid = threadIdx.x;
  const int bid = blockIdx.x;
  const int t   = bid % 3;          // column tile within row
  const int row = bid / 3;
  const int oi  = row % OH;
  const int b   = row / OH;
  const int par = oi & 1;           // active columns satisfy oj ≡ oi (mod 2)
  const int ap0 = t * 32;           // first active-column index of this tile

  float* outb = out + ((size_t)(b * OH + oi)) * OW * COUT;

  // ---- zero-fill opposite-parity columns covered by this tile ----
  {
    const int opar  = par ^ 1;
    const int noppo = (opar == 0) ? 65 : 64;
    const int q0 = ap0;
    const int q1 = min(q0 + 32, noppo);
    const int ncols = q1 - q0;
    if (ncols > 0) {
      const float4 z = make_float4(0.f, 0.f, 0.f, 0.f);
      for (int idx = tid; idx < ncols * 32; idx += 256) {
        int q  = q0 + (idx >> 5);
        int c4 = idx & 31;
        *(float4*)(outb + (opar + 2 * q) * COUT + c4 * 4) = z;
      }
    }
  }

  // ---- hex mask: valid iff |oi-100| + |oj-64| <= 128 (parity already ensured) ----
  int ad = oi - 100; ad = ad < 0 ? -ad : ad;
  const int lim  = 128 - ad;          // need |oj-64| <= lim
  const int ojlo = par + 2 * ap0;
  int ojhi = ojlo + 62;
  if (ojhi > OW - 1) ojhi = OW - 1;
  const bool any = (ojlo <= OW - 1) && (ojlo <= 64 + lim) && (ojhi >= 64 - lim);

  const int co_b = (tid & 31) * 4;
  const int p_b  = (tid >> 5) * 4;
  float acc[4][4] = {{0.f, 0.f, 0.f, 0.f}};

  if (any) {
    const float* xb = x + (size_t)b * (HH * WW * CIN);
    for (int k = 0; k < NTAP; ++k) {
      const int dh = c_dh[k];
      const int dw = c_dw[k];
      const float* xr = xb + (size_t)(oi + dh) * (WW * CIN);
      // stage x tile: 32 positions x 64 ci = 512 float4, 2/thread
      #pragma unroll
      for (int i = 0; i < 2; ++i) {
        int l  = tid + i * 256;      // [0,512)
        int p  = l >> 4;
        int c4 = l & 15;
        int col = par + 2 * (ap0 + p) + dw;
        if (col > WW - 1) col = WW - 1;   // clamp for out-of-range slots (discarded)
        *(float4*)(&xs[p][c4 * 4]) = *(const float4*)(xr + col * CIN + c4 * 4);
      }
      // stage weight tile for this tap: 64x128 = 2048 float4, 8/thread
      if (PACKED) {
        const float4* wsrc = (const float4*)(w + (size_t)k * CIN * COUT);
        #pragma unroll
        for (int i = 0; i < 8; ++i) {
          int l = tid + i * 256;
          ((float4*)ws)[l] = wsrc[l];
        }
      } else {
        #pragma unroll
        for (int i = 0; i < 32; ++i) {
          int l  = tid + i * 256;    // [0,8192)
          int ci = l >> 7;
          int co = l & 127;
          ws[ci][co] = w[ci * (COUT * NTAP) + co * NTAP + k];
        }
      }
      __syncthreads();

      // 4x4 register tile over (position, co); 8 ds_read_b128 per 64 FMA
      #pragma unroll
      for (int c4 = 0; c4 < 16; ++c4) {
        float a[4][4];
        #pragma unroll
        for (int pj = 0; pj < 4; ++pj) {
          float4 av = *(const float4*)(&xs[p_b + pj][c4 * 4]);
          a[pj][0] = av.x; a[pj][1] = av.y; a[pj][2] = av.z; a[pj][3] = av.w;
        }
        #pragma unroll
        for (int kk = 0; kk < 4; ++kk) {
          float4 wv = *(const float4*)(&ws[c4 * 4 + kk][co_b]);
          #pragma unroll
          for (int pj = 0; pj < 4; ++pj) {
            acc[pj][0] = fmaf(a[pj][kk], wv.x, acc[pj][0]);
            acc[pj][1] = fmaf(a[pj][kk], wv.y, acc[pj][1]);
            acc[pj][2] = fmaf(a[pj][kk], wv.z, acc[pj][2]);
            acc[pj][3] = fmaf(a[pj][kk], wv.w, acc[pj][3]);
          }
        }
      }
      __syncthreads();
    }
  }

  // ---- epilogue: elu(conv + offset) at valid slots, zeros elsewhere ----
  const float4 offv = *(const float4*)(offs + co_b);
  #pragma unroll
  for (int pj = 0; pj < 4; ++pj) {
    const int oj = par + 2 * (ap0 + p_b + pj);
    if (oj <= OW - 1) {
      int adj = oj - 64; adj = adj < 0 ? -adj : adj;
      float4 res;
      if (adj <= lim) {
        float v0 = acc[pj][0] + offv.x;
        float v1 = acc[pj][1] + offv.y;
        float v2 = acc[pj][2] + offv.z;
        float v3 = acc[pj][3] + offv.w;
        res.x = v0 > 0.f ? v0 : expm1f(v0);
        res.y = v1 > 0.f ? v1 : expm1f(v1);
        res.z = v2 > 0.f ? v2 : expm1f(v2);
        res.w = v3 > 0.f ? v3 : expm1f(v3);
      } else {
        res = make_float4(0.f, 0.f, 0.f, 0.f);
      }
      *(float4*)(outb + oj * COUT + co_b) = res;
    }
  }
}

extern "C" void kernel_launch(void* const* d_in, const int* in_sizes, int n_in,
                              void* d_out, int out_size, void* d_ws, size_t ws_size,
                              hipStream_t stream) {
  const float* x   = (const float*)d_in[0];
  const float* sw  = (const float*)d_in[1];
  const float* off = (const float*)d_in[2];
  float* out = (float*)d_out;

  const int nblocks = NB * OH * 3;   // 16*201*3 = 9648

  if (ws_size >= (size_t)NW * sizeof(float)) {
    float* wt = (float*)d_ws;
    repack_w<<<NW / 256, 256, 0, stream>>>(sw, wt);
    conv_hex<true><<<nblocks, 256, 0, stream>>>(x, wt, off, out);
  } else {
    conv_hex<false><<<nblocks, 256, 0, stream>>>(x, sw, off, out);
  }
}

// Round 2
// 463.098 us; speedup vs baseline: 2.6233x; 2.6233x over previous
//
#include <hip/hip_runtime.h>
#include <math.h>

#define NB   16
#define HH   209
#define WW   133
#define CIN  64
#define COUT 128
#define OH   201
#define OW   129
#define NTAP 19
#define NW   (NTAP*CIN*COUT)

#define XS_STRIDE 72   // bf16 elems per LDS row (64 + 8 pad; 144B rows keep 16B align, <=2-way banks)

typedef __attribute__((ext_vector_type(8))) __bf16 bf16x8;
typedef __attribute__((ext_vector_type(4))) float f32x4;
typedef __attribute__((ext_vector_type(4))) unsigned short us4;

// hex taps for R=2 in the 9x5 kernel grid (verified round 1)
__constant__ int c_dh[NTAP] = {4,3,5,6,5,3,2,1,2,4,6,7,8,7,6,4,2,1,0};
__constant__ int c_dw[NTAP] = {2,3,3,2,1,1,2,3,4,4,4,3,2,1,0,0,0,1,2};

__device__ __forceinline__ unsigned short f2bf(float f) {
  unsigned int u = __builtin_bit_cast(unsigned int, f);
  u += 0x7FFFu + ((u >> 16) & 1u);       // RNE
  return (unsigned short)(u >> 16);
}

// sparse_weights [ci][co][k] fp32  ->  wt [k][co][ci] bf16
__global__ __launch_bounds__(256) void repack_w(const float* __restrict__ w,
                                                unsigned short* __restrict__ wt) {
  int gid = blockIdx.x * 256 + threadIdx.x;   // dst index, coalesced writes
  int ci = gid & 63;
  int co = (gid >> 6) & 127;
  int k  = gid >> 13;
  wt[gid] = f2bf(w[ci * (COUT * NTAP) + co * NTAP + k]);
}

// one block per (b, oi): 4 waves, wave w -> co [32w, 32w+32); M = dynamic 16-frags over hex range
__global__ __launch_bounds__(256) void conv_hex_mfma(const float* __restrict__ x,
                                                     const unsigned short* __restrict__ wt,
                                                     const float* __restrict__ offs,
                                                     float* __restrict__ out) {
  __shared__ unsigned short xs[80 * XS_STRIDE];   // 11.25 KB: up to 80 positions x 64 ci (bf16)

  const int tid  = threadIdx.x;
  const int lane = tid & 63;
  const int wv   = tid >> 6;
  const int l15  = lane & 15;
  const int quad = lane >> 4;
  const int n0   = wv * 32;

  const int bid = blockIdx.x;
  const int oi  = bid % OH;
  const int b   = bid / OH;
  const int par = oi & 1;
  const int na  = 65 - par;                 // same-parity columns: a in [0, na)

  int ad = oi - 100; ad = ad < 0 ? -ad : ad;
  const int lim = 128 - ad;                 // valid iff |oj-64| <= lim (lim >= 28)

  // active-index range [a_lo, a_hi]
  int a_lo_raw = 64 - lim - par;
  int a_lo = a_lo_raw <= 0 ? 0 : (a_lo_raw + 1) >> 1;
  int a_hi = (64 + lim - par) >> 1;
  if (a_hi > na - 1) a_hi = na - 1;

  const int f0 = a_lo >> 4;
  const int f1 = a_hi >> 4;
  const int nf = f1 - f0 + 1;               // 1..5
  const int p0 = f0 * 16;

  float* outb = out + (size_t)(b * OH + oi) * OW * COUT;

  // ---- zero-fill: opposite-parity columns + same-parity outside computed frags ----
  {
    const float4 z = make_float4(0.f, 0.f, 0.f, 0.f);
    const int opar = par ^ 1;
    const int nopp = 65 - opar;
    for (int idx = tid; idx < nopp * 32; idx += 256) {
      int q  = idx >> 5;
      int c4 = idx & 31;
      *(float4*)(outb + (size_t)(opar + 2 * q) * COUT + c4 * 4) = z;
    }
    const int hi_start = p0 + nf * 16;
    const int hi_cnt   = na > hi_start ? na - hi_start : 0;
    const int tot      = (p0 + hi_cnt) * 32;
    for (int idx = tid; idx < tot; idx += 256) {
      int q  = idx >> 5;
      int a  = q < p0 ? q : hi_start + (q - p0);
      int c4 = idx & 31;
      *(float4*)(outb + (size_t)(par + 2 * a) * COUT + c4 * 4) = z;
    }
  }

  f32x4 acc[5][2];
  #pragma unroll
  for (int i = 0; i < 5; ++i) {
    #pragma unroll
    for (int j = 0; j < 2; ++j) acc[i][j] = (f32x4){0.f, 0.f, 0.f, 0.f};
  }

  const float* xb = x + (size_t)b * (HH * WW * CIN);

  for (int k = 0; k < NTAP; ++k) {
    const int dh = c_dh[k];
    const int dw = c_dw[k];

    // B fragments from global (L1/L2-hot 311 KB table), issued early
    bf16x8 bfrag[2][2];
    {
      const unsigned short* wb = wt + (size_t)k * CIN * COUT;
      #pragma unroll
      for (int j = 0; j < 2; ++j) {
        const unsigned short* wn = wb + (size_t)(n0 + j * 16 + l15) * CIN + quad * 8;
        bfrag[0][j] = *(const bf16x8*)(wn);
        bfrag[1][j] = *(const bf16x8*)(wn + 32);
      }
    }

    // stage A: nf*16 positions x 64 ci, fp32 -> bf16
    const float* xr = xb + (size_t)(oi + dh) * (WW * CIN);
    #pragma unroll 5
    for (int i = 0; i < nf; ++i) {
      int chunk = tid + i * 256;            // [0, nf*256)
      int prel  = chunk >> 4;
      int c4    = chunk & 15;
      int col   = par + 2 * (p0 + prel) + dw;
      if (col > WW - 1) col = WW - 1;       // clamp (results masked later)
      float4 v = *(const float4*)(xr + (size_t)col * CIN + c4 * 4);
      us4 o;
      o.x = f2bf(v.x); o.y = f2bf(v.y); o.z = f2bf(v.z); o.w = f2bf(v.w);
      *(us4*)(&xs[prel * XS_STRIDE + c4 * 4]) = o;
    }
    __syncthreads();

    #pragma unroll
    for (int ks = 0; ks < 2; ++ks) {
      #pragma unroll
      for (int mf = 0; mf < 5; ++mf) {
        if (mf < nf) {
          bf16x8 afrag = *(const bf16x8*)(&xs[(mf * 16 + l15) * XS_STRIDE + ks * 32 + quad * 8]);
          acc[mf][0] = __builtin_amdgcn_mfma_f32_16x16x32_bf16(afrag, bfrag[ks][0], acc[mf][0], 0, 0, 0);
          acc[mf][1] = __builtin_amdgcn_mfma_f32_16x16x32_bf16(afrag, bfrag[ks][1], acc[mf][1], 0, 0, 0);
        }
      }
    }
    __syncthreads();
  }

  // ---- epilogue: elu(conv + offset), hex-masked; C/D: col=lane&15, row=quad*4+reg ----
  const float off0 = offs[n0 + l15];
  const float off1 = offs[n0 + 16 + l15];
  #pragma unroll
  for (int mf = 0; mf < 5; ++mf) {
    if (mf < nf) {
      #pragma unroll
      for (int r = 0; r < 4; ++r) {
        int a  = (f0 + mf) * 16 + quad * 4 + r;
        int oj = par + 2 * a;
        if (oj <= OW - 1) {
          int adj = oj - 64; adj = adj < 0 ? -adj : adj;
          bool valid = adj <= lim;
          float v0 = acc[mf][0][r] + off0;
          float v1 = acc[mf][1][r] + off1;
          float e0 = v0 > 0.f ? v0 : expm1f(v0);
          float e1 = v1 > 0.f ? v1 : expm1f(v1);
          outb[(size_t)oj * COUT + n0 + l15]      = valid ? e0 : 0.f;
          outb[(size_t)oj * COUT + n0 + 16 + l15] = valid ? e1 : 0.f;
        }
      }
    }
  }
}

extern "C" void kernel_launch(void* const* d_in, const int* in_sizes, int n_in,
                              void* d_out, int out_size, void* d_ws, size_t ws_size,
                              hipStream_t stream) {
  const float* x   = (const float*)d_in[0];
  const float* sw  = (const float*)d_in[1];
  const float* off = (const float*)d_in[2];
  float* out = (float*)d_out;

  unsigned short* wtb = (unsigned short*)d_ws;     // 311 KB, ws_size verified >= 622 KB in round 1
  repack_w<<<NW / 256, 256, 0, stream>>>(sw, wtb);
  conv_hex_mfma<<<NB * OH, 256, 0, stream>>>(x, wtb, off, out);
}

// Round 3
// 414.879 us; speedup vs baseline: 2.9282x; 1.1162x over previous
//
#include <hip/hip_runtime.h>
#include <math.h>

#define NB   16
#define HH   209
#define WW   133
#define CIN  64
#define COUT 128
#define OH   201
#define OW   129
#define NTAP 19
#define NW   (NTAP*CIN*COUT)

#define XS 72   // bf16 elems per LDS row (64 + 8 pad; keeps 16B align, 2-way banks = free)

typedef __attribute__((ext_vector_type(8))) __bf16 bf16x8;
typedef __attribute__((ext_vector_type(4))) float f32x4;
typedef __attribute__((ext_vector_type(4))) unsigned short us4;

__device__ __forceinline__ unsigned short f2bf(float f) {
  unsigned int u = __builtin_bit_cast(unsigned int, f);
  u += 0x7FFFu + ((u >> 16) & 1u);       // RNE
  return (unsigned short)(u >> 16);
}

// sparse_weights [ci][co][k] fp32  ->  wt [k][co][ci] bf16
__global__ __launch_bounds__(256) void repack_w(const float* __restrict__ w,
                                                unsigned short* __restrict__ wt) {
  int gid = blockIdx.x * 256 + threadIdx.x;   // dst index, coalesced writes
  int ci = gid & 63;
  int co = (gid >> 6) & 127;
  int k  = gid >> 13;
  wt[gid] = f2bf(w[ci * (COUT * NTAP) + co * NTAP + k]);
}

// taps grouped by dh (row): within a dh all dw share parity -> one stride-2 window/row
// dh row r has c_cnt[r] taps starting at c_start[r] in c_k/c_dw order
// (verified vs round-1/2 tap tables)
__global__ __launch_bounds__(256) void conv_hex_mfma(const float* __restrict__ x,
                                                     const unsigned short* __restrict__ wt,
                                                     const float* __restrict__ offs,
                                                     float* __restrict__ out) {
  constexpr int c_start[9] = {0, 1, 3, 6, 8, 11, 13, 16, 18};
  constexpr int c_cnt[9]   = {1, 2, 3, 2, 3, 2, 3, 2, 1};
  constexpr int c_k[19]  = {18, 7,17, 6, 8,16, 1, 5, 0, 9,15, 2, 4, 3,10,14, 11,13, 12};
  constexpr int c_dw[19] = { 2, 3, 1, 2, 4, 0, 3, 1, 2, 4, 0, 3, 1, 2, 4, 0, 3, 1, 2};

  __shared__ unsigned short xs[2][82 * XS];   // 2 x 11.8 KB double buffer

  const int tid  = threadIdx.x;
  const int lane = tid & 63;
  const int wv   = tid >> 6;
  const int l15  = lane & 15;
  const int quad = lane >> 4;
  const int n0   = wv * 32;

  const int bid = blockIdx.x;
  const int oi  = bid % OH;
  const int b   = bid / OH;
  const int par = oi & 1;
  const int na  = 65 - par;                 // same-parity columns: a in [0, na)

  int ad = oi - 100; ad = ad < 0 ? -ad : ad;
  const int lim = 128 - ad;                 // valid iff |oj-64| <= lim

  int a_lo_raw = 64 - lim - par;
  int a_lo = a_lo_raw <= 0 ? 0 : (a_lo_raw + 1) >> 1;
  int a_hi = (64 + lim - par) >> 1;
  if (a_hi > na - 1) a_hi = na - 1;

  const int f0 = a_lo >> 4;
  const int f1 = a_hi >> 4;
  const int nf = f1 - f0 + 1;               // 1..5
  const int p0 = f0 * 16;
  const int npos   = nf * 16;
  const int nchunk = (npos + 2) * 16;       // float4 chunks to stage per x-row

  float* outb = out + (size_t)(b * OH + oi) * OW * COUT;

  // ---- zero-fill: opposite-parity columns + same-parity outside computed frags ----
  {
    const float4 z = make_float4(0.f, 0.f, 0.f, 0.f);
    const int opar = par ^ 1;
    const int nopp = 65 - opar;
    for (int idx = tid; idx < nopp * 32; idx += 256) {
      int q  = idx >> 5;
      int c4 = idx & 31;
      *(float4*)(outb + (size_t)(opar + 2 * q) * COUT + c4 * 4) = z;
    }
    const int hi_start = p0 + npos;
    const int hi_cnt   = na > hi_start ? na - hi_start : 0;
    const int tot      = (p0 + hi_cnt) * 32;
    for (int idx = tid; idx < tot; idx += 256) {
      int q  = idx >> 5;
      int a  = q < p0 ? q : hi_start + (q - p0);
      int c4 = idx & 31;
      *(float4*)(outb + (size_t)(par + 2 * a) * COUT + c4 * 4) = z;
    }
  }

  f32x4 acc[5][2];
  #pragma unroll
  for (int i = 0; i < 5; ++i)
    #pragma unroll
    for (int j = 0; j < 2; ++j) acc[i][j] = (f32x4){0.f, 0.f, 0.f, 0.f};

  const float* xb = x + (size_t)b * (HH * WW * CIN);

  float4 stg[6];
  bf16x8 bfrag[3][2][2];

  auto load_stg = [&](int r) {
    const float* xr = xb + (size_t)(oi + r) * (WW * CIN);
    const int rpar = (par + r) & 1;
    #pragma unroll
    for (int i = 0; i < 6; ++i) {
      int c = tid + i * 256;
      if (c < nchunk) {
        int j  = c >> 4;
        int c4 = c & 15;
        int col = rpar + 2 * (p0 + j);
        if (col > WW - 1) col = WW - 1;    // clamp; results masked in epilogue
        stg[i] = *(const float4*)(xr + (size_t)col * CIN + c4 * 4);
      }
    }
  };
  auto store_stg = [&](int buf) {
    #pragma unroll
    for (int i = 0; i < 6; ++i) {
      int c = tid + i * 256;
      if (c < nchunk) {
        int j  = c >> 4;
        int c4 = c & 15;
        us4 o;
        o.x = f2bf(stg[i].x); o.y = f2bf(stg[i].y);
        o.z = f2bf(stg[i].z); o.w = f2bf(stg[i].w);
        *(us4*)(&xs[buf][j * XS + c4 * 4]) = o;
      }
    }
  };

  // prologue: stage x-row 0 into buf 0
  load_stg(0);
  store_stg(0);

  #pragma unroll
  for (int r = 0; r < 9; ++r) {
    // B fragments for this row's taps FIRST (so waiting on B leaves stg in flight)
    {
      const int st = c_start[r], cnt = c_cnt[r];
      #pragma unroll
      for (int t = 0; t < 3; ++t) {
        if (t < cnt) {
          const unsigned short* wb = wt + (size_t)c_k[st + t] * (CIN * COUT);
          #pragma unroll
          for (int j = 0; j < 2; ++j) {
            const unsigned short* wn = wb + (size_t)(n0 + j * 16 + l15) * CIN + quad * 8;
            bfrag[t][0][j] = *(const bf16x8*)(wn);
            bfrag[t][1][j] = *(const bf16x8*)(wn + 32);
          }
        }
      }
    }
    if (r < 8) load_stg(r + 1);            // x-globals for next row, stay in flight
    __syncthreads();                       // buf r&1 ready for all waves

    // compute taps of row r from buf r&1
    {
      const int st = c_start[r], cnt = c_cnt[r];
      const unsigned short* bufp = xs[r & 1];
      #pragma unroll
      for (int t = 0; t < 3; ++t) {
        if (t < cnt) {
          const int s = (par + c_dw[st + t]) >> 1;   // position shift of this tap
          #pragma unroll
          for (int ks = 0; ks < 2; ++ks) {
            #pragma unroll
            for (int mf = 0; mf < 5; ++mf) {
              if (mf < nf) {
                bf16x8 a = *(const bf16x8*)(&bufp[(mf * 16 + l15 + s) * XS + ks * 32 + quad * 8]);
                acc[mf][0] = __builtin_amdgcn_mfma_f32_16x16x32_bf16(a, bfrag[t][ks][0], acc[mf][0], 0, 0, 0);
                acc[mf][1] = __builtin_amdgcn_mfma_f32_16x16x32_bf16(a, bfrag[t][ks][1], acc[mf][1], 0, 0, 0);
              }
            }
          }
        }
      }
    }

    if (r < 8) store_stg((r + 1) & 1);     // convert+write next row; readers of this buf
                                           // finished before the barrier above
  }

  // ---- epilogue: elu(conv + offset), hex-masked; C/D: col=lane&15, row=quad*4+reg ----
  const float off0 = offs[n0 + l15];
  const float off1 = offs[n0 + 16 + l15];
  #pragma unroll
  for (int mf = 0; mf < 5; ++mf) {
    if (mf < nf) {
      #pragma unroll
      for (int r = 0; r < 4; ++r) {
        int a  = (f0 + mf) * 16 + quad * 4 + r;
        int oj = par + 2 * a;
        if (oj <= OW - 1) {
          int adj = oj - 64; adj = adj < 0 ? -adj : adj;
          bool valid = adj <= lim;
          float v0 = acc[mf][0][r] + off0;
          float v1 = acc[mf][1][r] + off1;
          float e0 = v0 > 0.f ? v0 : expm1f(v0);
          float e1 = v1 > 0.f ? v1 : expm1f(v1);
          outb[(size_t)oj * COUT + n0 + l15]      = valid ? e0 : 0.f;
          outb[(size_t)oj * COUT + n0 + 16 + l15] = valid ? e1 : 0.f;
        }
      }
    }
  }
}

extern "C" void kernel_launch(void* const* d_in, const int* in_sizes, int n_in,
                              void* d_out, int out_size, void* d_ws, size_t ws_size,
                              hipStream_t stream) {
  const float* x   = (const float*)d_in[0];
  const float* sw  = (const float*)d_in[1];
  const float* off = (const float*)d_in[2];
  float* out = (float*)d_out;

  unsigned short* wtb = (unsigned short*)d_ws;     // 311 KB
  repack_w<<<NW / 256, 256, 0, stream>>>(sw, wtb);
  conv_hex_mfma<<<NB * OH, 256, 0, stream>>>(x, wtb, off, out);
}